// Round 3
// baseline (260.258 us; speedup 1.0000x reference)
//
#include <hip/hip_runtime.h>
#include <stdint.h>

typedef unsigned short ushort_t;
typedef __attribute__((ext_vector_type(8))) short short8v;   // 8 x bf16
typedef __attribute__((ext_vector_type(4))) float f32x4;     // MFMA acc

// ws: At bf16 [16][128][512] (2 MiB) | Wt bf16 [16][512][512] (8 MiB)
#define AT_ELEMS (16u * 128u * 512u)
#define WT_ELEMS (16u * 512u * 512u)
#define WS_NEEDED ((size_t)(AT_ELEMS + WT_ELEMS) * 2u)

__host__ __device__ constexpr int ga_sign_i(int a, int b) {
  int t = a >> 1, sw = 0;
  while (t) {
    int x = t & b;
    while (x) { sw += x & 1; x >>= 1; }
    t >>= 1;
  }
  return (sw & 1) ? -1 : 1;
}

struct SignTab { int s[16][16]; };
constexpr SignTab make_tab() {
  SignTab t{};
  for (int i = 0; i < 16; i++)
    for (int j = 0; j < 16; j++) t.s[i][j] = ga_sign_i(i, j);
  return t;
}
constexpr SignTab STAB = make_tab();

__device__ __forceinline__ ushort_t f2bf(float f) {
  unsigned u = __float_as_uint(f);
  u = (u + 0x7FFFu + ((u >> 16) & 1u)) >> 16;   // RNE
  return (ushort_t)u;
}

__device__ __forceinline__ short8v neg_bf16x8(short8v v) {
  const short m = (short)0x8000;
  return v ^ (short8v){m, m, m, m, m, m, m, m};
}

// ---------------------------------------------------------------------------
// prep (unchanged, proven): At[j][b][n] = bf16(x[b,n,j]); Wt[j][u][n] = bf16(w[u,n,j])
// ---------------------------------------------------------------------------
#define PREP_XT (128 * 512)
#define PREP_TOT (PREP_XT + 512 * 512)   // 327,680 -> 1280 blocks

__global__ __launch_bounds__(256) void prep_kernel(const float* __restrict__ x,
                                                   const float* __restrict__ w,
                                                   ushort_t* __restrict__ At,
                                                   ushort_t* __restrict__ Wt) {
  int tid = blockIdx.x * 256 + threadIdx.x;
  if (tid < PREP_XT) {
    int n = tid & 511, b = tid >> 9;
    const float4* xp = (const float4*)(x + (size_t)tid * 16);
    float v[16];
#pragma unroll
    for (int qq = 0; qq < 4; qq++) {
      float4 t = xp[qq];
      v[qq * 4 + 0] = t.x; v[qq * 4 + 1] = t.y; v[qq * 4 + 2] = t.z; v[qq * 4 + 3] = t.w;
    }
#pragma unroll
    for (int j = 0; j < 16; j++)
      At[((size_t)(j * 128 + b)) * 512 + n] = f2bf(v[j]);
  } else {
    int t = tid - PREP_XT;
    int n = t & 511, u = t >> 9;
    const float4* wp = (const float4*)(w + (size_t)t * 16);
    float v[16];
#pragma unroll
    for (int qq = 0; qq < 4; qq++) {
      float4 tt = wp[qq];
      v[qq * 4 + 0] = tt.x; v[qq * 4 + 1] = tt.y; v[qq * 4 + 2] = tt.z; v[qq * 4 + 3] = tt.w;
    }
#pragma unroll
    for (int j = 0; j < 16; j++)
      Wt[((size_t)(j * 512 + u)) * 512 + n] = f2bf(v[j]);
  }
}

// ---------------------------------------------------------------------------
// gemm v4 = v3 pipeline with the R2 bug fixed.
// R2 ROOT CAUSE: LDS dest of global_load_lds was tid*16 (per-lane, divergent).
// HW semantics (m104): dest = WAVE-UNIFORM base + lane*16. Divergent dest =>
// compiler waterfalls per lane (~64 single-lane 16B transactions per instr):
// gemm 192us, FETCH 70MB (6x overfetch), MfmaUtil 3.5%. readfirstlane(tid*16)
// == wv*1024 == intended base, so numerics passed - only perf died.
// FIX: dest byte offset = wv*1024 (wave-uniform, v1's proven idiom). The
// per-lane SOURCE map (srow2=tid>>3, ip, row, sps) already decomposes exactly
// as HW's base+lane*16 layout: ip=wv>>1, row=(wv&1)*8+(lane>>3), sps=lane&7.
//
// Pipeline (unchanged from v3): stage = 64 n (A 32K | W 32K), double-buffered
// in 128 KB LDS. Per stage: issue next-stage DMA first, ds_read + 128 MFMA
// per wave on current buffer, then vmcnt(0) (drains under MFMA) + s_barrier.
// Waves partition (n-half wn x j-half wj); epilogue 4-wave sum is
// partition-agnostic. Swizzle slot = p ^ (row&7) on 128 B rows.
// ---------------------------------------------------------------------------
__global__ __launch_bounds__(256, 1) void gemm_kernel(const ushort_t* __restrict__ At,
                                                      const ushort_t* __restrict__ Wt,
                                                      const float* __restrict__ bias,
                                                      float* __restrict__ out) {
  __shared__ __align__(16) ushort_t smem[65536];   // 128 KB: buf0 @0, buf1 @64 KB (A 32K | W 32K each)

  const int ut = blockIdx.x;       // 0..31
  const int bt = blockIdx.y;       // 0..7
  const int u0 = ut * 16, b0 = bt * 16;

  const int tid = threadIdx.x;
  const int wv = tid >> 6, lane = tid & 63;
  const int la = lane & 15, q = lane >> 4;
  const int wn = wv >> 1, wj = wv & 1;   // n-half, j-half

  // --- staging (DMA) per-lane SOURCE map (matches HW dest = base + lane*16) ---
  const int srow2 = tid >> 3;            // 0..31
  const int ip = srow2 >> 4;             // plane parity (i = 2m + ip)
  const int row = srow2 & 15;
  const int sps = tid & 7;               // slot in the 128 B row
  const int sp = sps ^ (row & 7);        // content chunk (8 elems) at this slot

  const ushort_t* Abase = At + (size_t)(ip * 128 + b0 + row) * 512 + sp * 8;
  const ushort_t* Wbase = Wt + (size_t)(ip * 512 + u0 + row) * 512 + sp * 8;

  // --- staging DMA dest: WAVE-UNIFORM byte base (HW appends lane*16) ---
  const int sdst = wv * 1024;            // wave's quarter of each 4 KB plane-pair

  // --- frag read: byte offset within a 2 KB (16 row x 128 B) plane ---
  const int lbx = la * 128 + ((((wn << 2) | q) ^ (la & 7)) * 16);

  f32x4 acc[16];
#pragma unroll
  for (int k = 0; k < 16; k++) acc[k] = (f32x4){0.f, 0.f, 0.f, 0.f};

#define STAGE(BUFB, SN)                                                                       \
  do {                                                                                        \
    _Pragma("unroll")                                                                         \
    for (int m = 0; m < 8; m++) {                                                             \
      __builtin_amdgcn_global_load_lds(                                                       \
          (const __attribute__((address_space(1))) unsigned int*)(Abase + (size_t)m * 131072 + (size_t)(SN) * 64), \
          (__attribute__((address_space(3))) unsigned int*)(&smem[((BUFB) + m * 4096 + sdst) >> 1]),                \
          16, 0, 0);                                                                          \
      __builtin_amdgcn_global_load_lds(                                                       \
          (const __attribute__((address_space(1))) unsigned int*)(Wbase + (size_t)m * 524288 + (size_t)(SN) * 64), \
          (__attribute__((address_space(3))) unsigned int*)(&smem[((BUFB) + 32768 + m * 4096 + sdst) >> 1]),        \
          16, 0, 0);                                                                          \
    }                                                                                         \
  } while (0)

  // prologue: fill buf0 with stage 0; full drain + barrier once.
  STAGE(0, 0);
  __syncthreads();

#pragma unroll 1
  for (int s = 0; s < 8; s++) {
    const int cb = (s & 1) << 16;        // current buffer byte offset
    if (s < 7) STAGE(cb ^ 65536, s + 1); // prefetch next stage into other buffer

    const char* smb = (const char*)smem + cb;
    short8v av[16], nav[16];
#pragma unroll
    for (int i = 0; i < 16; i++) {
      av[i] = *(const short8v*)(smb + i * 2048 + lbx);
      nav[i] = neg_bf16x8(av[i]);
    }
#pragma unroll
    for (int jj = 0; jj < 8; jj++) {
      const int j = wj * 8 + jj;
      const short8v bvj = *(const short8v*)(smb + 32768 + j * 2048 + lbx);
#pragma unroll
      for (int k = 0; k < 16; k++) {
        const int i = j ^ k;                 // compile-time after unroll
        acc[k] = __builtin_amdgcn_mfma_f32_16x16x32_bf16(
            (STAB.s[i][j] < 0) ? nav[i] : av[i], bvj, acc[k], 0, 0, 0);
      }
    }

    // Drain own prefetch (landed under the MFMA phase), then publish.
    asm volatile("s_waitcnt vmcnt(0)" ::: "memory");
    __builtin_amdgcn_s_barrier();
  }
#undef STAGE

  // --- epilogue: cross-wave reduction + bias + coalesced float4 out ---
  float* red = (float*)smem;   // reuse first 64 KB: [wv][row16][col16][k16] f32
#pragma unroll
  for (int g = 0; g < 4; g++) {
#pragma unroll
    for (int r2 = 0; r2 < 4; r2++) {
      float4 v = make_float4(acc[g * 4 + 0][r2], acc[g * 4 + 1][r2],
                             acc[g * 4 + 2][r2], acc[g * 4 + 3][r2]);
      int orow = q * 4 + r2;                 // C/D: row = quad*4 + reg (m89)
      *(float4*)&red[(((wv * 16 + orow) * 16 + la) << 4) + g * 4] = v;
    }
  }
  __syncthreads();

  const int orow = tid >> 4, col = tid & 15;
  float4 o[4];
#pragma unroll
  for (int g = 0; g < 4; g++)
    o[g] = *(const float4*)&bias[(u0 + col) * 16 + g * 4];
#pragma unroll
  for (int w2 = 0; w2 < 4; w2++) {
#pragma unroll
    for (int g = 0; g < 4; g++) {
      float4 v = *(const float4*)&red[(((w2 * 16 + orow) * 16 + col) << 4) + g * 4];
      o[g].x += v.x; o[g].y += v.y; o[g].z += v.z; o[g].w += v.w;
    }
  }
#pragma unroll
  for (int g = 0; g < 4; g++)
    *(float4*)&out[((size_t)(b0 + orow) * 512 + (u0 + col)) * 16 + g * 4] = o[g];
}

// ---------------------------------------------------------------------------
// fallback (ws too small): exact fp32, slow but correct
// ---------------------------------------------------------------------------
__global__ __launch_bounds__(256) void naive_kernel(const float* __restrict__ x,
                                                    const float* __restrict__ w,
                                                    const float* __restrict__ bias,
                                                    float* __restrict__ out) {
  int t = blockIdx.x * 256 + threadIdx.x;
  if (t >= 128 * 512 * 16) return;
  int k = t & 15;
  int u = (t >> 4) & 511;
  int b = t >> 13;
  float sgn[16];
#pragma unroll
  for (int i = 0; i < 16; i++) sgn[i] = (float)ga_sign_i(i, i ^ k);
  float acc = bias[u * 16 + k];
  for (int n = 0; n < 512; n++) {
    const float* xp = x + ((size_t)(b * 512 + n)) * 16;
    const float* wp = w + ((size_t)(u * 512 + n)) * 16;
#pragma unroll
    for (int i = 0; i < 16; i++)
      acc += xp[i] * sgn[i] * wp[i ^ k];
  }
  out[t] = acc;
}

extern "C" void kernel_launch(void* const* d_in, const int* in_sizes, int n_in,
                              void* d_out, int out_size, void* d_ws, size_t ws_size,
                              hipStream_t stream) {
  const float* x    = (const float*)d_in[0];
  const float* w    = (const float*)d_in[1];
  const float* bias = (const float*)d_in[2];
  float* out = (float*)d_out;

  if (ws_size >= WS_NEEDED && d_ws != nullptr) {
    ushort_t* At = (ushort_t*)d_ws;
    ushort_t* Wt = At + AT_ELEMS;

    prep_kernel<<<PREP_TOT / 256, 256, 0, stream>>>(x, w, At, Wt);
    gemm_kernel<<<dim3(32, 8), 256, 0, stream>>>(At, Wt, bias, out);
  } else {
    naive_kernel<<<(128 * 512 * 16) / 256, 256, 0, stream>>>(x, w, bias, out);
  }
}

// Round 4
// 96.443 us; speedup vs baseline: 2.6986x; 2.6986x over previous
//
#include <hip/hip_runtime.h>
#include <stdint.h>

typedef unsigned short ushort_t;
typedef __attribute__((ext_vector_type(8))) short short8v;   // 8 x bf16
typedef __attribute__((ext_vector_type(4))) float f32x4;     // MFMA acc

// ws: At bf16 [16][128][512] (2 MiB) | Wt bf16 [16][512][512] (8 MiB)
#define AT_ELEMS (16u * 128u * 512u)
#define WT_ELEMS (16u * 512u * 512u)
#define WS_NEEDED ((size_t)(AT_ELEMS + WT_ELEMS) * 2u)

__host__ __device__ constexpr int ga_sign_i(int a, int b) {
  int t = a >> 1, sw = 0;
  while (t) {
    int x = t & b;
    while (x) { sw += x & 1; x >>= 1; }
    t >>= 1;
  }
  return (sw & 1) ? -1 : 1;
}

struct SignTab { int s[16][16]; };
constexpr SignTab make_tab() {
  SignTab t{};
  for (int i = 0; i < 16; i++)
    for (int j = 0; j < 16; j++) t.s[i][j] = ga_sign_i(i, j);
  return t;
}
constexpr SignTab STAB = make_tab();

__device__ __forceinline__ ushort_t f2bf(float f) {
  unsigned u = __float_as_uint(f);
  u = (u + 0x7FFFu + ((u >> 16) & 1u)) >> 16;   // RNE
  return (ushort_t)u;
}

__device__ __forceinline__ short8v neg_bf16x8(short8v v) {
  const short m = (short)0x8000;
  return v ^ (short8v){m, m, m, m, m, m, m, m};
}

// ---------------------------------------------------------------------------
// prep (R0, proven): At[j][b][n] = bf16(x[b,n,j]); Wt[j][u][n] = bf16(w[u,n,j])
// ---------------------------------------------------------------------------
#define PREP_XT (128 * 512)
#define PREP_TOT (PREP_XT + 512 * 512)   // 327,680 -> 1280 blocks

__global__ __launch_bounds__(256) void prep_kernel(const float* __restrict__ x,
                                                   const float* __restrict__ w,
                                                   ushort_t* __restrict__ At,
                                                   ushort_t* __restrict__ Wt) {
  int tid = blockIdx.x * 256 + threadIdx.x;
  if (tid < PREP_XT) {
    int n = tid & 511, b = tid >> 9;
    const float4* xp = (const float4*)(x + (size_t)tid * 16);
    float v[16];
#pragma unroll
    for (int qq = 0; qq < 4; qq++) {
      float4 t = xp[qq];
      v[qq * 4 + 0] = t.x; v[qq * 4 + 1] = t.y; v[qq * 4 + 2] = t.z; v[qq * 4 + 3] = t.w;
    }
#pragma unroll
    for (int j = 0; j < 16; j++)
      At[((size_t)(j * 128 + b)) * 512 + n] = f2bf(v[j]);
  } else {
    int t = tid - PREP_XT;
    int n = t & 511, u = t >> 9;
    const float4* wp = (const float4*)(w + (size_t)t * 16);
    float v[16];
#pragma unroll
    for (int qq = 0; qq < 4; qq++) {
      float4 tt = wp[qq];
      v[qq * 4 + 0] = tt.x; v[qq * 4 + 1] = tt.y; v[qq * 4 + 2] = tt.z; v[qq * 4 + 3] = tt.w;
    }
#pragma unroll
    for (int j = 0; j < 16; j++)
      Wt[((size_t)(j * 512 + u)) * 512 + n] = f2bf(v[j]);
  }
}

// ---------------------------------------------------------------------------
// gemm v5 = EXACT R0 (94.5us-proven) structure: same staging map, same swizzle
// (slot = p ^ (row&7) on 256B rows), same single-buffer 4-stage schedule with
// __syncthreads drains, same epilogue. ONE change vs R0: the inner loop is
// reordered j-outer -> i-outer to cut register pressure:
//   R0:  av[16] + nav[16] live across the whole j-loop   (~128 VGPR + acc)
//   v5:  bv[16] cached (64 VGPR); a/na transient (8 VGPR) per i-step
// Same MFMA set (i = j^k pairs), same 32 ds_reads/wave/kt, same sign table;
// only the f32 accumulation order over (i,j) changes (tolerance-neutral).
// Rationale: v3/v4's unexplained 200us regression + anomalous WRITE_SIZE is
// most consistent with register-pressure pathology in the restructured loop;
// this change is strictly pressure-reducing while preserving the proven
// schedule. Worst case: neutral (baseline restored).
// ---------------------------------------------------------------------------
__global__ __launch_bounds__(256, 1) void gemm_kernel(const ushort_t* __restrict__ At,
                                                      const ushort_t* __restrict__ Wt,
                                                      const float* __restrict__ bias,
                                                      float* __restrict__ out) {
  __shared__ __align__(16) ushort_t smem[65536];   // 128 KB

  const int ut = blockIdx.x;       // 0..31
  const int bt = blockIdx.y;       // 0..7
  const int u0 = ut * 16, b0 = bt * 16;

  const int tid = threadIdx.x;
  const int wv = tid >> 6, lane = tid & 63;
  const int la = lane & 15, q = lane >> 4;

  // --- staging (DMA) addressing: thread -> (row = tid>>4, ps = tid&15) ---
  const int srow = tid >> 4;
  const int sps = tid & 15;
  const int sp = sps ^ (srow & 7);          // content position in the 256B row
  const int sc = sp >> 2, sq = sp & 3;      // n = c*32 + q*8 (+ kt*128)

  const ushort_t* AxB = At + (size_t)(b0 + srow) * 512 + sc * 32 + sq * 8;
  const ushort_t* WxB = Wt + (size_t)(u0 + srow) * 512 + sc * 32 + sq * 8;

  // --- frag read addressing ---
  const int pr = wv * 4 + q;                          // this wave's n-quarter, this quad's 16B pos
  const int lbx = la * 256 + ((pr ^ (la & 7)) * 16);  // byte offset within a j-block (4096 B)

  f32x4 acc[16];
#pragma unroll
  for (int k = 0; k < 16; k++) acc[k] = (f32x4){0.f, 0.f, 0.f, 0.f};

  const char* sm = (const char*)smem;

#pragma unroll 1
  for (int kt = 0; kt < 4; kt++) {
#pragma unroll
    for (int i = 0; i < 16; i++)
      __builtin_amdgcn_global_load_lds(
          (const __attribute__((address_space(1))) unsigned int*)(AxB + (size_t)i * 65536 + kt * 128),
          (__attribute__((address_space(3))) unsigned int*)(&smem[(i * 256 + wv * 64) * 8]),
          16, 0, 0);
#pragma unroll
    for (int i = 0; i < 16; i++)
      __builtin_amdgcn_global_load_lds(
          (const __attribute__((address_space(1))) unsigned int*)(WxB + (size_t)i * 262144 + kt * 128),
          (__attribute__((address_space(3))) unsigned int*)(&smem[32768 + (i * 256 + wv * 64) * 8]),
          16, 0, 0);
    __syncthreads();

    // B-frags cached for the whole kt (64 VGPR); A-frags transient per i.
    short8v bv[16];
#pragma unroll
    for (int j = 0; j < 16; j++)
      bv[j] = *(const short8v*)(sm + 65536 + j * 4096 + lbx);

#pragma unroll
    for (int i = 0; i < 16; i++) {
      const short8v a = *(const short8v*)(sm + i * 4096 + lbx);
      const short8v na = neg_bf16x8(a);
#pragma unroll
      for (int j = 0; j < 16; j++) {
        const int k = i ^ j;                 // compile-time after unroll
        acc[k] = __builtin_amdgcn_mfma_f32_16x16x32_bf16(
            (STAB.s[i][j] < 0) ? na : a, bv[j], acc[k], 0, 0, 0);
      }
    }
    __syncthreads();
  }

  // --- epilogue: cross-wave reduction + bias + coalesced float4 out ---
  float* red = (float*)smem;   // reuse first 64 KB: [wv][row16][col16][k16] f32
#pragma unroll
  for (int g = 0; g < 4; g++) {
#pragma unroll
    for (int r2 = 0; r2 < 4; r2++) {
      float4 v = make_float4(acc[g * 4 + 0][r2], acc[g * 4 + 1][r2],
                             acc[g * 4 + 2][r2], acc[g * 4 + 3][r2]);
      int row = q * 4 + r2;                  // C/D: row = quad*4 + reg (m89)
      *(float4*)&red[(((wv * 16 + row) * 16 + la) << 4) + g * 4] = v;
    }
  }
  __syncthreads();

  const int row = tid >> 4, col = tid & 15;
  float4 o[4];
#pragma unroll
  for (int g = 0; g < 4; g++)
    o[g] = *(const float4*)&bias[(u0 + col) * 16 + g * 4];
#pragma unroll
  for (int w2 = 0; w2 < 4; w2++) {
#pragma unroll
    for (int g = 0; g < 4; g++) {
      float4 v = *(const float4*)&red[(((w2 * 16 + row) * 16 + col) << 4) + g * 4];
      o[g].x += v.x; o[g].y += v.y; o[g].z += v.z; o[g].w += v.w;
    }
  }
#pragma unroll
  for (int g = 0; g < 4; g++)
    *(float4*)&out[((size_t)(b0 + row) * 512 + (u0 + col)) * 16 + g * 4] = o[g];
}

// ---------------------------------------------------------------------------
// fallback (ws too small): exact fp32, slow but correct
// ---------------------------------------------------------------------------
__global__ __launch_bounds__(256) void naive_kernel(const float* __restrict__ x,
                                                    const float* __restrict__ w,
                                                    const float* __restrict__ bias,
                                                    float* __restrict__ out) {
  int t = blockIdx.x * 256 + threadIdx.x;
  if (t >= 128 * 512 * 16) return;
  int k = t & 15;
  int u = (t >> 4) & 511;
  int b = t >> 13;
  float sgn[16];
#pragma unroll
  for (int i = 0; i < 16; i++) sgn[i] = (float)ga_sign_i(i, i ^ k);
  float acc = bias[u * 16 + k];
  for (int n = 0; n < 512; n++) {
    const float* xp = x + ((size_t)(b * 512 + n)) * 16;
    const float* wp = w + ((size_t)(u * 512 + n)) * 16;
#pragma unroll
    for (int i = 0; i < 16; i++)
      acc += xp[i] * sgn[i] * wp[i ^ k];
  }
  out[t] = acc;
}

extern "C" void kernel_launch(void* const* d_in, const int* in_sizes, int n_in,
                              void* d_out, int out_size, void* d_ws, size_t ws_size,
                              hipStream_t stream) {
  const float* x    = (const float*)d_in[0];
  const float* w    = (const float*)d_in[1];
  const float* bias = (const float*)d_in[2];
  float* out = (float*)d_out;

  if (ws_size >= WS_NEEDED && d_ws != nullptr) {
    ushort_t* At = (ushort_t*)d_ws;
    ushort_t* Wt = At + AT_ELEMS;

    prep_kernel<<<PREP_TOT / 256, 256, 0, stream>>>(x, w, At, Wt);
    gemm_kernel<<<dim3(32, 8), 256, 0, stream>>>(At, Wt, bias, out);
  } else {
    naive_kernel<<<(128 * 512 * 16) / 256, 256, 0, stream>>>(x, w, bias, out);
  }
}

// Round 5
// 95.521 us; speedup vs baseline: 2.7246x; 1.0097x over previous
//
#include <hip/hip_runtime.h>
#include <stdint.h>

typedef unsigned short ushort_t;
typedef __attribute__((ext_vector_type(8))) short short8v;   // 8 x bf16
typedef __attribute__((ext_vector_type(4))) float f32x4;     // MFMA acc

// ws: At bf16 [16][128][512] (2 MiB) | Wt bf16 [16][512][512] (8 MiB)
#define AT_ELEMS (16u * 128u * 512u)
#define WT_ELEMS (16u * 512u * 512u)
#define WS_NEEDED ((size_t)(AT_ELEMS + WT_ELEMS) * 2u)

__host__ __device__ constexpr int ga_sign_i(int a, int b) {
  int t = a >> 1, sw = 0;
  while (t) {
    int x = t & b;
    while (x) { sw += x & 1; x >>= 1; }
    t >>= 1;
  }
  return (sw & 1) ? -1 : 1;
}

struct SignTab { int s[16][16]; };
constexpr SignTab make_tab() {
  SignTab t{};
  for (int i = 0; i < 16; i++)
    for (int j = 0; j < 16; j++) t.s[i][j] = ga_sign_i(i, j);
  return t;
}
constexpr SignTab STAB = make_tab();

__device__ __forceinline__ ushort_t f2bf(float f) {
  unsigned u = __float_as_uint(f);
  u = (u + 0x7FFFu + ((u >> 16) & 1u)) >> 16;   // RNE
  return (ushort_t)u;
}

__device__ __forceinline__ short8v neg_bf16x8(short8v v) {
  const short m = (short)0x8000;
  return v ^ (short8v){m, m, m, m, m, m, m, m};
}

// ---------------------------------------------------------------------------
// prep v2: LDS-transpose. One block per source row (b of x, or u of w).
// Phase 1: 256 threads load the row (512n x 16 blades, 32 KB f32) fully
//   vectorized (8x float4/thread), convert to bf16, scatter into a 16 KB LDS
//   tile Ls[16 blade][512 n] (scalar b16 writes, ~4-way conflicts, cheap).
// Phase 2: read Ls as short8 (b128, 2-way/4-way conflict-free pattern) and
//   store 16 B/lane; each 16-lane group writes a 256 B contiguous segment of
//   At[j][row][*] / Wt[j][row][*].
// vs prep v1: store instrs 16 -> 4 per thread, store width 2 B -> 16 B.
// At/Wt layouts BIT-IDENTICAL to v1 -> gemm untouched.
// Grid: 128 (x rows) + 512 (w rows) = 640 blocks; 16 KB LDS -> ~2.5 blocks/CU.
// ---------------------------------------------------------------------------
#define PREP_BLOCKS (128 + 512)

__global__ __launch_bounds__(256) void prep_kernel(const float* __restrict__ x,
                                                   const float* __restrict__ w,
                                                   ushort_t* __restrict__ At,
                                                   ushort_t* __restrict__ Wt) {
  __shared__ __align__(16) ushort_t Ls[16 * 512];   // 16 KB: Ls[i][n]

  const int r = blockIdx.x;
  const int t = threadIdx.x;
  const bool isx = (r < 128);
  const float* src = isx ? (x + (size_t)r * 8192) : (w + (size_t)(r - 128) * 8192);
  ushort_t* dst    = isx ? (At + (size_t)r * 512)  : (Wt + (size_t)(r - 128) * 512);
  const int dplane = isx ? (128 * 512) : (512 * 512);

  // Phase 1: load + convert + LDS transpose-write.
  // unit uu in [0,1024): 8 consecutive f32 = (n = uu>>1, blade-half i0 = (uu&1)*8)
#pragma unroll
  for (int k = 0; k < 4; k++) {
    const int uu = t + k * 256;
    const float4* sp = (const float4*)(src + (size_t)uu * 8);
    const float4 v0 = sp[0], v1 = sp[1];
    const int n = uu >> 1, i0 = (uu & 1) * 8;
    ushort_t* lp = &Ls[i0 * 512 + n];
    lp[0]    = f2bf(v0.x); lp[512]  = f2bf(v0.y);
    lp[1024] = f2bf(v0.z); lp[1536] = f2bf(v0.w);
    lp[2048] = f2bf(v1.x); lp[2560] = f2bf(v1.y);
    lp[3072] = f2bf(v1.z); lp[3584] = f2bf(v1.w);
  }
  __syncthreads();

  // Phase 2: vectorized store. thread = (j = t>>4, c = t&15); 4 chunks of 8 n.
  const int j = t >> 4, c = t & 15;
#pragma unroll
  for (int g = 0; g < 4; g++) {
    const int chunk = c + g * 16;                       // n8 index 0..63
    const short8v vv = *(const short8v*)&Ls[j * 512 + chunk * 8];
    *(short8v*)(dst + (size_t)j * dplane + chunk * 8) = vv;
  }
}

// ---------------------------------------------------------------------------
// gemm v5 (UNCHANGED from Round 4, measured 96.4 total): R0 staging map,
// swizzle slot = p ^ (row&7) on 256B rows, single-buffer 4-stage schedule,
// i-outer inner loop (bv[16] cached, a/na transient), proven epilogue.
// ---------------------------------------------------------------------------
__global__ __launch_bounds__(256, 1) void gemm_kernel(const ushort_t* __restrict__ At,
                                                      const ushort_t* __restrict__ Wt,
                                                      const float* __restrict__ bias,
                                                      float* __restrict__ out) {
  __shared__ __align__(16) ushort_t smem[65536];   // 128 KB

  const int ut = blockIdx.x;       // 0..31
  const int bt = blockIdx.y;       // 0..7
  const int u0 = ut * 16, b0 = bt * 16;

  const int tid = threadIdx.x;
  const int wv = tid >> 6, lane = tid & 63;
  const int la = lane & 15, q = lane >> 4;

  // --- staging (DMA) addressing: thread -> (row = tid>>4, ps = tid&15) ---
  const int srow = tid >> 4;
  const int sps = tid & 15;
  const int sp = sps ^ (srow & 7);          // content position in the 256B row
  const int sc = sp >> 2, sq = sp & 3;      // n = c*32 + q*8 (+ kt*128)

  const ushort_t* AxB = At + (size_t)(b0 + srow) * 512 + sc * 32 + sq * 8;
  const ushort_t* WxB = Wt + (size_t)(u0 + srow) * 512 + sc * 32 + sq * 8;

  // --- frag read addressing ---
  const int pr = wv * 4 + q;                          // this wave's n-quarter, this quad's 16B pos
  const int lbx = la * 256 + ((pr ^ (la & 7)) * 16);  // byte offset within a j-block (4096 B)

  f32x4 acc[16];
#pragma unroll
  for (int k = 0; k < 16; k++) acc[k] = (f32x4){0.f, 0.f, 0.f, 0.f};

  const char* sm = (const char*)smem;

#pragma unroll 1
  for (int kt = 0; kt < 4; kt++) {
#pragma unroll
    for (int i = 0; i < 16; i++)
      __builtin_amdgcn_global_load_lds(
          (const __attribute__((address_space(1))) unsigned int*)(AxB + (size_t)i * 65536 + kt * 128),
          (__attribute__((address_space(3))) unsigned int*)(&smem[(i * 256 + wv * 64) * 8]),
          16, 0, 0);
#pragma unroll
    for (int i = 0; i < 16; i++)
      __builtin_amdgcn_global_load_lds(
          (const __attribute__((address_space(1))) unsigned int*)(WxB + (size_t)i * 262144 + kt * 128),
          (__attribute__((address_space(3))) unsigned int*)(&smem[32768 + (i * 256 + wv * 64) * 8]),
          16, 0, 0);
    __syncthreads();

    // B-frags cached for the whole kt (64 VGPR); A-frags transient per i.
    short8v bv[16];
#pragma unroll
    for (int j = 0; j < 16; j++)
      bv[j] = *(const short8v*)(sm + 65536 + j * 4096 + lbx);

#pragma unroll
    for (int i = 0; i < 16; i++) {
      const short8v a = *(const short8v*)(sm + i * 4096 + lbx);
      const short8v na = neg_bf16x8(a);
#pragma unroll
      for (int j = 0; j < 16; j++) {
        const int k = i ^ j;                 // compile-time after unroll
        acc[k] = __builtin_amdgcn_mfma_f32_16x16x32_bf16(
            (STAB.s[i][j] < 0) ? na : a, bv[j], acc[k], 0, 0, 0);
      }
    }
    __syncthreads();
  }

  // --- epilogue: cross-wave reduction + bias + coalesced float4 out ---
  float* red = (float*)smem;   // reuse first 64 KB: [wv][row16][col16][k16] f32
#pragma unroll
  for (int g = 0; g < 4; g++) {
#pragma unroll
    for (int r2 = 0; r2 < 4; r2++) {
      float4 v = make_float4(acc[g * 4 + 0][r2], acc[g * 4 + 1][r2],
                             acc[g * 4 + 2][r2], acc[g * 4 + 3][r2]);
      int row = q * 4 + r2;                  // C/D: row = quad*4 + reg (m89)
      *(float4*)&red[(((wv * 16 + row) * 16 + la) << 4) + g * 4] = v;
    }
  }
  __syncthreads();

  const int row = tid >> 4, col = tid & 15;
  float4 o[4];
#pragma unroll
  for (int g = 0; g < 4; g++)
    o[g] = *(const float4*)&bias[(u0 + col) * 16 + g * 4];
#pragma unroll
  for (int w2 = 0; w2 < 4; w2++) {
#pragma unroll
    for (int g = 0; g < 4; g++) {
      float4 v = *(const float4*)&red[(((w2 * 16 + row) * 16 + col) << 4) + g * 4];
      o[g].x += v.x; o[g].y += v.y; o[g].z += v.z; o[g].w += v.w;
    }
  }
#pragma unroll
  for (int g = 0; g < 4; g++)
    *(float4*)&out[((size_t)(b0 + row) * 512 + (u0 + col)) * 16 + g * 4] = o[g];
}

// ---------------------------------------------------------------------------
// fallback (ws too small): exact fp32, slow but correct
// ---------------------------------------------------------------------------
__global__ __launch_bounds__(256) void naive_kernel(const float* __restrict__ x,
                                                    const float* __restrict__ w,
                                                    const float* __restrict__ bias,
                                                    float* __restrict__ out) {
  int t = blockIdx.x * 256 + threadIdx.x;
  if (t >= 128 * 512 * 16) return;
  int k = t & 15;
  int u = (t >> 4) & 511;
  int b = t >> 13;
  float sgn[16];
#pragma unroll
  for (int i = 0; i < 16; i++) sgn[i] = (float)ga_sign_i(i, i ^ k);
  float acc = bias[u * 16 + k];
  for (int n = 0; n < 512; n++) {
    const float* xp = x + ((size_t)(b * 512 + n)) * 16;
    const float* wp = w + ((size_t)(u * 512 + n)) * 16;
#pragma unroll
    for (int i = 0; i < 16; i++)
      acc += xp[i] * sgn[i] * wp[i ^ k];
  }
  out[t] = acc;
}

extern "C" void kernel_launch(void* const* d_in, const int* in_sizes, int n_in,
                              void* d_out, int out_size, void* d_ws, size_t ws_size,
                              hipStream_t stream) {
  const float* x    = (const float*)d_in[0];
  const float* w    = (const float*)d_in[1];
  const float* bias = (const float*)d_in[2];
  float* out = (float*)d_out;

  if (ws_size >= WS_NEEDED && d_ws != nullptr) {
    ushort_t* At = (ushort_t*)d_ws;
    ushort_t* Wt = At + AT_ELEMS;

    prep_kernel<<<PREP_BLOCKS, 256, 0, stream>>>(x, w, At, Wt);
    gemm_kernel<<<dim3(32, 8), 256, 0, stream>>>(At, Wt, bias, out);
  } else {
    naive_kernel<<<(128 * 512 * 16) / 256, 256, 0, stream>>>(x, w, bias, out);
  }
}

// Round 6
// 94.603 us; speedup vs baseline: 2.7510x; 1.0097x over previous
//
#include <hip/hip_runtime.h>
#include <stdint.h>

typedef unsigned short ushort_t;
typedef __attribute__((ext_vector_type(8))) short short8v;   // 8 x bf16
typedef __attribute__((ext_vector_type(4))) float f32x4;     // MFMA acc

// ws: At bf16 [16][128][512] (2 MiB) | Wt bf16 [16][512][512] (8 MiB)
#define AT_ELEMS (16u * 128u * 512u)
#define WT_ELEMS (16u * 512u * 512u)
#define WS_NEEDED ((size_t)(AT_ELEMS + WT_ELEMS) * 2u)

__host__ __device__ constexpr int ga_sign_i(int a, int b) {
  int t = a >> 1, sw = 0;
  while (t) {
    int x = t & b;
    while (x) { sw += x & 1; x >>= 1; }
    t >>= 1;
  }
  return (sw & 1) ? -1 : 1;
}

struct SignTab { int s[16][16]; };
constexpr SignTab make_tab() {
  SignTab t{};
  for (int i = 0; i < 16; i++)
    for (int j = 0; j < 16; j++) t.s[i][j] = ga_sign_i(i, j);
  return t;
}
constexpr SignTab STAB = make_tab();

__device__ __forceinline__ ushort_t f2bf(float f) {
  unsigned u = __float_as_uint(f);
  u = (u + 0x7FFFu + ((u >> 16) & 1u)) >> 16;   // RNE
  return (ushort_t)u;
}

__device__ __forceinline__ short8v neg_bf16x8(short8v v) {
  const short m = (short)0x8000;
  return v ^ (short8v){m, m, m, m, m, m, m, m};
}

// ---------------------------------------------------------------------------
// prep v2 (kept from Round 5, neutral-to-slightly-positive): LDS-transpose,
// one block per source row; fully vectorized loads, short8 stores.
// At/Wt layouts bit-identical to v1 -> gemm untouched.
// ---------------------------------------------------------------------------
#define PREP_BLOCKS (128 + 512)

__global__ __launch_bounds__(256) void prep_kernel(const float* __restrict__ x,
                                                   const float* __restrict__ w,
                                                   ushort_t* __restrict__ At,
                                                   ushort_t* __restrict__ Wt) {
  __shared__ __align__(16) ushort_t Ls[16 * 512];   // 16 KB: Ls[i][n]

  const int r = blockIdx.x;
  const int t = threadIdx.x;
  const bool isx = (r < 128);
  const float* src = isx ? (x + (size_t)r * 8192) : (w + (size_t)(r - 128) * 8192);
  ushort_t* dst    = isx ? (At + (size_t)r * 512)  : (Wt + (size_t)(r - 128) * 512);
  const int dplane = isx ? (128 * 512) : (512 * 512);

  // Phase 1: load + convert + LDS transpose-write.
#pragma unroll
  for (int k = 0; k < 4; k++) {
    const int uu = t + k * 256;
    const float4* sp = (const float4*)(src + (size_t)uu * 8);
    const float4 v0 = sp[0], v1 = sp[1];
    const int n = uu >> 1, i0 = (uu & 1) * 8;
    ushort_t* lp = &Ls[i0 * 512 + n];
    lp[0]    = f2bf(v0.x); lp[512]  = f2bf(v0.y);
    lp[1024] = f2bf(v0.z); lp[1536] = f2bf(v0.w);
    lp[2048] = f2bf(v1.x); lp[2560] = f2bf(v1.y);
    lp[3072] = f2bf(v1.z); lp[3584] = f2bf(v1.w);
  }
  __syncthreads();

  // Phase 2: vectorized store.
  const int j = t >> 4, c = t & 15;
#pragma unroll
  for (int g = 0; g < 4; g++) {
    const int chunk = c + g * 16;                       // n8 index 0..63
    const short8v vv = *(const short8v*)&Ls[j * 512 + chunk * 8];
    *(short8v*)(dst + (size_t)j * dplane + chunk * 8) = vv;
  }
}

// ---------------------------------------------------------------------------
// gemm v6 = gemm v5 (R0 proven structure, i-outer loop) + T1 XCD-aware block
// remap. ONLY change vs the 95.5us-measured kernel: grid flattened to 256 and
// (ut, bt) derived so each XCD owns a contiguous 4-ut stripe x all 8 bt.
// Mechanism: default x-fast mapping round-robins consecutive ut across XCDs,
// so each XCD's 32 resident blocks stream ALL of Wt (8 MB) through its 4 MB
// L2 -> ~70 MB L3/HBM re-fetch (matches v3/v4's measured FETCH_SIZE) and
// L3-latency stage drains, fully exposed at 1 wave/SIMD. With the stripe map,
// per-XCD working set = 4x256KB (Wt) + 8x256KB (At) = 3 MB < 4 MB L2 ->
// staging becomes L2-hit after first touch.
// Map: xcd = bid&7 (HW round-robins linear wg id across 8 XCDs, m09/HK),
//      local = bid>>3, ut = xcd*4 + (local&3), bt = local>>2. Bijective:
//      bid = (ut>>2)*1... inverse: xcd=ut>>2? no: xcd owns ut in [4*xcd,4*xcd+4)
//      -> xcd = ut/4, local = bt*4 + (ut&3), bid = local*8 + xcd. Unique. ✓
// Everything else (staging map, swizzle, __syncthreads schedule, inner loop,
// epilogue) byte-identical to the measured kernel.
// ---------------------------------------------------------------------------
__global__ __launch_bounds__(256, 1) void gemm_kernel(const ushort_t* __restrict__ At,
                                                      const ushort_t* __restrict__ Wt,
                                                      const float* __restrict__ bias,
                                                      float* __restrict__ out) {
  __shared__ __align__(16) ushort_t smem[65536];   // 128 KB

  const int bid = blockIdx.x;          // 0..255
  const int xcd = bid & 7;             // HW XCD round-robin on linear wg id
  const int local = bid >> 3;          // 0..31 within this XCD
  const int ut = xcd * 4 + (local & 3);   // 0..31: 4-ut stripe per XCD
  const int bt = local >> 2;              // 0..7
  const int u0 = ut * 16, b0 = bt * 16;

  const int tid = threadIdx.x;
  const int wv = tid >> 6, lane = tid & 63;
  const int la = lane & 15, q = lane >> 4;

  // --- staging (DMA) addressing: thread -> (row = tid>>4, ps = tid&15) ---
  const int srow = tid >> 4;
  const int sps = tid & 15;
  const int sp = sps ^ (srow & 7);          // content position in the 256B row
  const int sc = sp >> 2, sq = sp & 3;      // n = c*32 + q*8 (+ kt*128)

  const ushort_t* AxB = At + (size_t)(b0 + srow) * 512 + sc * 32 + sq * 8;
  const ushort_t* WxB = Wt + (size_t)(u0 + srow) * 512 + sc * 32 + sq * 8;

  // --- frag read addressing ---
  const int pr = wv * 4 + q;                          // this wave's n-quarter, this quad's 16B pos
  const int lbx = la * 256 + ((pr ^ (la & 7)) * 16);  // byte offset within a j-block (4096 B)

  f32x4 acc[16];
#pragma unroll
  for (int k = 0; k < 16; k++) acc[k] = (f32x4){0.f, 0.f, 0.f, 0.f};

  const char* sm = (const char*)smem;

#pragma unroll 1
  for (int kt = 0; kt < 4; kt++) {
#pragma unroll
    for (int i = 0; i < 16; i++)
      __builtin_amdgcn_global_load_lds(
          (const __attribute__((address_space(1))) unsigned int*)(AxB + (size_t)i * 65536 + kt * 128),
          (__attribute__((address_space(3))) unsigned int*)(&smem[(i * 256 + wv * 64) * 8]),
          16, 0, 0);
#pragma unroll
    for (int i = 0; i < 16; i++)
      __builtin_amdgcn_global_load_lds(
          (const __attribute__((address_space(1))) unsigned int*)(WxB + (size_t)i * 262144 + kt * 128),
          (__attribute__((address_space(3))) unsigned int*)(&smem[32768 + (i * 256 + wv * 64) * 8]),
          16, 0, 0);
    __syncthreads();

    // B-frags cached for the whole kt (64 VGPR); A-frags transient per i.
    short8v bv[16];
#pragma unroll
    for (int j = 0; j < 16; j++)
      bv[j] = *(const short8v*)(sm + 65536 + j * 4096 + lbx);

#pragma unroll
    for (int i = 0; i < 16; i++) {
      const short8v a = *(const short8v*)(sm + i * 4096 + lbx);
      const short8v na = neg_bf16x8(a);
#pragma unroll
      for (int j = 0; j < 16; j++) {
        const int k = i ^ j;                 // compile-time after unroll
        acc[k] = __builtin_amdgcn_mfma_f32_16x16x32_bf16(
            (STAB.s[i][j] < 0) ? na : a, bv[j], acc[k], 0, 0, 0);
      }
    }
    __syncthreads();
  }

  // --- epilogue: cross-wave reduction + bias + coalesced float4 out ---
  float* red = (float*)smem;   // reuse first 64 KB: [wv][row16][col16][k16] f32
#pragma unroll
  for (int g = 0; g < 4; g++) {
#pragma unroll
    for (int r2 = 0; r2 < 4; r2++) {
      float4 v = make_float4(acc[g * 4 + 0][r2], acc[g * 4 + 1][r2],
                             acc[g * 4 + 2][r2], acc[g * 4 + 3][r2]);
      int row = q * 4 + r2;                  // C/D: row = quad*4 + reg (m89)
      *(float4*)&red[(((wv * 16 + row) * 16 + la) << 4) + g * 4] = v;
    }
  }
  __syncthreads();

  const int row = tid >> 4, col = tid & 15;
  float4 o[4];
#pragma unroll
  for (int g = 0; g < 4; g++)
    o[g] = *(const float4*)&bias[(u0 + col) * 16 + g * 4];
#pragma unroll
  for (int w2 = 0; w2 < 4; w2++) {
#pragma unroll
    for (int g = 0; g < 4; g++) {
      float4 v = *(const float4*)&red[(((w2 * 16 + row) * 16 + col) << 4) + g * 4];
      o[g].x += v.x; o[g].y += v.y; o[g].z += v.z; o[g].w += v.w;
    }
  }
#pragma unroll
  for (int g = 0; g < 4; g++)
    *(float4*)&out[((size_t)(b0 + row) * 512 + (u0 + col)) * 16 + g * 4] = o[g];
}

// ---------------------------------------------------------------------------
// fallback (ws too small): exact fp32, slow but correct
// ---------------------------------------------------------------------------
__global__ __launch_bounds__(256) void naive_kernel(const float* __restrict__ x,
                                                    const float* __restrict__ w,
                                                    const float* __restrict__ bias,
                                                    float* __restrict__ out) {
  int t = blockIdx.x * 256 + threadIdx.x;
  if (t >= 128 * 512 * 16) return;
  int k = t & 15;
  int u = (t >> 4) & 511;
  int b = t >> 13;
  float sgn[16];
#pragma unroll
  for (int i = 0; i < 16; i++) sgn[i] = (float)ga_sign_i(i, i ^ k);
  float acc = bias[u * 16 + k];
  for (int n = 0; n < 512; n++) {
    const float* xp = x + ((size_t)(b * 512 + n)) * 16;
    const float* wp = w + ((size_t)(u * 512 + n)) * 16;
#pragma unroll
    for (int i = 0; i < 16; i++)
      acc += xp[i] * sgn[i] * wp[i ^ k];
  }
  out[t] = acc;
}

extern "C" void kernel_launch(void* const* d_in, const int* in_sizes, int n_in,
                              void* d_out, int out_size, void* d_ws, size_t ws_size,
                              hipStream_t stream) {
  const float* x    = (const float*)d_in[0];
  const float* w    = (const float*)d_in[1];
  const float* bias = (const float*)d_in[2];
  float* out = (float*)d_out;

  if (ws_size >= WS_NEEDED && d_ws != nullptr) {
    ushort_t* At = (ushort_t*)d_ws;
    ushort_t* Wt = At + AT_ELEMS;

    prep_kernel<<<PREP_BLOCKS, 256, 0, stream>>>(x, w, At, Wt);
    gemm_kernel<<<256, 256, 0, stream>>>(At, Wt, bias, out);
  } else {
    naive_kernel<<<(128 * 512 * 16) / 256, 256, 0, stream>>>(x, w, bias, out);
  }
}